// Round 5
// baseline (250.967 us; speedup 1.0000x reference)
//
#include <hip/hip_runtime.h>
#include <hip/hip_bf16.h>

#define NEG_SLOPE 0.2f
#define LN_EPS 1e-5f
#define SM_EPS 1e-16f

typedef __attribute__((ext_vector_type(8))) short bf16x8;
typedef __attribute__((ext_vector_type(4))) float f32x4;

__device__ inline unsigned short f2bf(float f) {
    unsigned u = __float_as_uint(f);
    return (unsigned short)((u + 0x7FFFu + ((u >> 16) & 1u)) >> 16);
}
__device__ inline float bf_lo(unsigned int v) { return __uint_as_float(v << 16); }
__device__ inline float bf_hi(unsigned int v) { return __uint_as_float(v & 0xffff0000u); }

#define NBIN2 2048         // bins = dst>>6 (64 dsts per bin); 1563 occupied at N=100k
#define BCAP2 1344         // slots per bin: mean E/1563 ~= 1024, sigma ~32 -> +10 sigma
#define DPB 64             // dsts per bin
#define SCHUNK 4096        // edges per scatter block (16/thread)
#define CURPAD 16          // binCursor stride in ints -> one counter per 64B line

// ---------------------------------------------------------------------------
// K1: bf16-MFMA GEMM + attention dots + bf16 pack. (binCursor is now
// initialized by hipMemsetAsync: cursors are bin-relative.)
// ---------------------------------------------------------------------------
__global__ __launch_bounds__(256) void k_gemm(const float* __restrict__ X,
                                              const float* __restrict__ W,
                                              const float* __restrict__ att_src,
                                              const float* __restrict__ att_dst,
                                              unsigned int* __restrict__ xp,
                                              float2* __restrict__ aS,
                                              float2* __restrict__ aD, int N) {
    __shared__ unsigned short Ws[128 * 136];
    __shared__ unsigned short Xs[64 * 136];
    const int t = threadIdx.x;
    const int b0 = blockIdx.x * 64;
    const int lane = t & 63;
    const int w = t >> 6;
    const int c15 = lane & 15;
    const int quad = lane >> 4;

#pragma unroll
    for (int i = 0; i < 16; ++i) {
        int f = i * 256 + t;
        int nr = f >> 5;
        int q = f & 31;
        float4 v = reinterpret_cast<const float4*>(W)[nr * 32 + q];
        ushort4 b;
        b.x = f2bf(v.x); b.y = f2bf(v.y); b.z = f2bf(v.z); b.w = f2bf(v.w);
        *reinterpret_cast<ushort4*>(&Ws[nr * 136 + q * 4]) = b;
    }
#pragma unroll
    for (int i = 0; i < 8; ++i) {
        int f = i * 256 + t;
        int m = f >> 5;
        int q = f & 31;
        int gr = b0 + m;
        if (gr >= N) gr = N - 1;
        float4 v = reinterpret_cast<const float4*>(X)[(size_t)gr * 32 + q];
        ushort4 b;
        b.x = f2bf(v.x); b.y = f2bf(v.y); b.z = f2bf(v.z); b.w = f2bf(v.w);
        *reinterpret_cast<ushort4*>(&Xs[m * 136 + q * 4]) = b;
    }
    __syncthreads();

    f32x4 acc[8];
#pragma unroll
    for (int ct = 0; ct < 8; ++ct) acc[ct] = (f32x4){0.f, 0.f, 0.f, 0.f};

#pragma unroll
    for (int kc = 0; kc < 4; ++kc) {
        bf16x8 af = *reinterpret_cast<const bf16x8*>(
            &Xs[(w * 16 + c15) * 136 + kc * 32 + quad * 8]);
#pragma unroll
        for (int ct = 0; ct < 8; ++ct) {
            bf16x8 bfr = *reinterpret_cast<const bf16x8*>(
                &Ws[(ct * 16 + c15) * 136 + kc * 32 + quad * 8]);
            acc[ct] = __builtin_amdgcn_mfma_f32_16x16x32_bf16(af, bfr, acc[ct], 0, 0, 0);
        }
    }

    float attS[8], attD[8];
#pragma unroll
    for (int ct = 0; ct < 8; ++ct) {
        attS[ct] = att_src[ct * 16 + c15];
        attD[ct] = att_dst[ct * 16 + c15];
    }

#pragma unroll
    for (int r = 0; r < 4; ++r) {
        int row = b0 + w * 16 + quad * 4 + r;
        float s0 = 0.f, s1 = 0.f, d0 = 0.f, d1 = 0.f;
#pragma unroll
        for (int ct = 0; ct < 4; ++ct) {
            s0 += acc[ct][r] * attS[ct];
            d0 += acc[ct][r] * attD[ct];
            s1 += acc[ct + 4][r] * attS[ct + 4];
            d1 += acc[ct + 4][r] * attD[ct + 4];
        }
#pragma unroll
        for (int o = 1; o < 16; o <<= 1) {
            s0 += __shfl_xor(s0, o);
            s1 += __shfl_xor(s1, o);
            d0 += __shfl_xor(d0, o);
            d1 += __shfl_xor(d1, o);
        }
        if (row < N) {
#pragma unroll
            for (int ct = 0; ct < 4; ++ct) {
                unsigned int p = (unsigned int)f2bf(acc[ct][r]) |
                                 ((unsigned int)f2bf(acc[ct + 4][r]) << 16);
                xp[(size_t)row * 64 + ct * 16 + c15] = p;
            }
            if (c15 == 0) {
                aS[row] = make_float2(s0, s1);
                aD[row] = make_float2(d0, d1);
            }
        }
    }
}

// ---------------------------------------------------------------------------
// k_scatter: pure streaming binner into 64-dst bins. 16 edges per thread;
// payload 4B {(dst&63)<<26 | src} (src < 2^26).
// Pass 1: LDS chunk-histogram; reserve per-(block,bin) ranges via one global
// atomicAdd per non-empty bin (bin-relative, line-padded cursors).
// Pass 2: scatter into tmp.
// ---------------------------------------------------------------------------
__global__ __launch_bounds__(256) void k_scatter(const int* __restrict__ ei,
                                                 int* __restrict__ binCursor,
                                                 unsigned int* __restrict__ tmp,
                                                 int E) {
    __shared__ int off[NBIN2];
    const int t = threadIdx.x;
    const int base = blockIdx.x * SCHUNK;

    int bn[16];
    unsigned int pe[16];
#pragma unroll
    for (int k = 0; k < 16; ++k) {
        int i = base + k * 256 + t;
        if (i < E) {
            int s = ei[i];
            int d = ei[E + i];
            bn[k] = d >> 6;
            pe[k] = ((unsigned)(d & 63) << 26) | (unsigned)s;
        } else {
            bn[k] = -1;
        }
    }

    for (int i = t; i < NBIN2; i += 256) off[i] = 0;
    __syncthreads();
#pragma unroll
    for (int k = 0; k < 16; ++k)
        if (bn[k] >= 0) atomicAdd(&off[bn[k]], 1);
    __syncthreads();
    for (int i = t; i < NBIN2; i += 256) {
        int h = off[i];
        off[i] = h ? (atomicAdd(&binCursor[i * CURPAD], h) + i * BCAP2) : 0;
    }
    __syncthreads();
#pragma unroll
    for (int k = 0; k < 16; ++k) {
        if (bn[k] >= 0) {
            int p = atomicAdd(&off[bn[k]], 1);
            tmp[p] = pe[k];
        }
    }
}

// ---------------------------------------------------------------------------
// k_fused: replaces k_bucket + k_agg. One block per 64-dst bin (1563 blocks,
// 256 threads, ~12.5KB LDS -> 8 blocks/CU, up to 32 waves/CU).
//   P1: read tmp slice once; each LANE owns an edge: gather aS[src] (L2-hot),
//       leaky+exp (no wave-redundant transcendentals, no readlane), pack u01
//       bf16x2, LDS count + f32 den atomics; edge kept in registers.
//   P2: 64-wide exclusive scan (wave 0).
//   P3: place {src,u01} into LDS ebuf sorted by dst (counting sort — the
//       tmp->csr global round-trip of k_bucket is gone).
//   P4: wave w aggregates dsts [w*16, w*16+16): register S0/S1, uniform LDS
//       entry reads (broadcast), xp gathers, then bias + LayerNorm.
// ---------------------------------------------------------------------------
__global__ __launch_bounds__(256) void k_fused(const unsigned int* __restrict__ xp,
                                               const float2* __restrict__ aS,
                                               const float2* __restrict__ aD,
                                               const unsigned int* __restrict__ tmp,
                                               const int* __restrict__ binCursor,
                                               const float* __restrict__ bias,
                                               const float* __restrict__ gamma,
                                               const float* __restrict__ beta,
                                               float* __restrict__ out, int N) {
    __shared__ int cnt[DPB];
    __shared__ int cur[DPB];
    __shared__ int beg[DPB];
    __shared__ float den0[DPB], den1[DPB];
    __shared__ float2 adc[DPB];
    __shared__ uint2 ebuf[BCAP2];
    const int t = threadIdx.x;
    const int b = blockIdx.x;
    const int start = b * BCAP2;
    const int d0 = b * DPB;
    int m = binCursor[b * CURPAD];
    if (m > BCAP2) m = BCAP2;   // statistically unreachable guard

    if (t < DPB) {
        cnt[t] = 0; den0[t] = 0.f; den1[t] = 0.f;
        int d = d0 + t;
        adc[t] = (d < N) ? aD[d] : make_float2(0.f, 0.f);
    }
    __syncthreads();

    // P1: weights + count + denominators (lane-parallel over edges)
    unsigned int ee[6], uu[6];
#pragma unroll
    for (int it = 0; it < 6; ++it) {
        int k = t + it * 256;
        ee[it] = 0xFFFFFFFFu;           // s < 2^26 -> sentinel unreachable
        if (k < m) {
            unsigned int e = tmp[start + k];
            ee[it] = e;
            int li = e >> 26;
            int s = (int)(e & 0x03FFFFFFu);
            float2 as2 = aS[s];
            float2 ad2 = adc[li];
            float g0 = as2.x + ad2.x; g0 = fmaxf(g0, NEG_SLOPE * g0);
            float g1 = as2.y + ad2.y; g1 = fmaxf(g1, NEG_SLOPE * g1);
            unsigned int u01 = (unsigned)f2bf(__expf(g0)) |
                               ((unsigned)f2bf(__expf(g1)) << 16);
            uu[it] = u01;
            atomicAdd(&cnt[li], 1);
            atomicAdd(&den0[li], bf_lo(u01));
            atomicAdd(&den1[li], bf_hi(u01));
        }
    }
    __syncthreads();

    // P2: exclusive scan over 64 dst counts (wave 0 only)
    if (t < DPB) {
        int v = cnt[t];
        int incl = v;
#pragma unroll
        for (int o = 1; o < 64; o <<= 1) {
            int u = __shfl_up(incl, o);
            if (t >= o) incl += u;
        }
        beg[t] = incl - v;
        cur[t] = incl - v;
    }
    __syncthreads();

    // P3: counting-sort placement into ebuf
#pragma unroll
    for (int it = 0; it < 6; ++it) {
        if (ee[it] != 0xFFFFFFFFu) {
            int li = ee[it] >> 26;
            int p = atomicAdd(&cur[li], 1);
            ebuf[p] = make_uint2(ee[it] & 0x03FFFFFFu, uu[it]);
        }
    }
    __syncthreads();

    // P4: per-dst aggregation + bias + LayerNorm (wave w: 16 dsts)
    const int w = t >> 6, lane = t & 63;
    for (int dd = 0; dd < 16; ++dd) {
        int li = w * 16 + dd;
        int n = d0 + li;
        if (n >= N) break;

        float2 a = aS[n];
        float2 ad2 = adc[li];
        float f0 = a.x + ad2.x; f0 = fmaxf(f0, NEG_SLOPE * f0);
        float f1 = a.y + ad2.y; f1 = fmaxf(f1, NEG_SLOPE * f1);
        float us0 = __expf(f0), us1 = __expf(f1);

        unsigned int vself = xp[((unsigned)n << 6) | lane];
        float S0 = us0 * bf_lo(vself);
        float S1 = us1 * bf_hi(vself);
        float inv0 = 0.5f / (den0[li] + us0 + SM_EPS);
        float inv1 = 0.5f / (den1[li] + us1 + SM_EPS);

        const int jb = beg[li];
        const int je = jb + cnt[li];
        int j = jb;
        for (; j + 3 < je; j += 4) {
            uint2 c0 = ebuf[j];
            uint2 c1 = ebuf[j + 1];
            uint2 c2 = ebuf[j + 2];
            uint2 c3 = ebuf[j + 3];
            unsigned int v0 = xp[(c0.x << 6) | lane];
            unsigned int v1 = xp[(c1.x << 6) | lane];
            unsigned int v2 = xp[(c2.x << 6) | lane];
            unsigned int v3 = xp[(c3.x << 6) | lane];
            S0 = fmaf(bf_lo(c0.y), bf_lo(v0), S0);
            S1 = fmaf(bf_hi(c0.y), bf_hi(v0), S1);
            S0 = fmaf(bf_lo(c1.y), bf_lo(v1), S0);
            S1 = fmaf(bf_hi(c1.y), bf_hi(v1), S1);
            S0 = fmaf(bf_lo(c2.y), bf_lo(v2), S0);
            S1 = fmaf(bf_hi(c2.y), bf_hi(v2), S1);
            S0 = fmaf(bf_lo(c3.y), bf_lo(v3), S0);
            S1 = fmaf(bf_hi(c3.y), bf_hi(v3), S1);
        }
        for (; j < je; ++j) {
            uint2 c = ebuf[j];
            unsigned int vv = xp[(c.x << 6) | lane];
            S0 = fmaf(bf_lo(c.y), bf_lo(vv), S0);
            S1 = fmaf(bf_hi(c.y), bf_hi(vv), S1);
        }

        float o = inv0 * S0 + inv1 * S1 + bias[lane];

        float mu = o;
#pragma unroll
        for (int d = 32; d > 0; d >>= 1) mu += __shfl_xor(mu, d);
        mu *= (1.0f / 64.0f);
        float dv = o - mu;
        float var = dv * dv;
#pragma unroll
        for (int d = 32; d > 0; d >>= 1) var += __shfl_xor(var, d);
        var *= (1.0f / 64.0f);
        out[(size_t)n * 64 + lane] =
            dv * rsqrtf(var + LN_EPS) * gamma[lane] + beta[lane];
    }
}

// ---------------------------------------------------------------------------
extern "C" void kernel_launch(void* const* d_in, const int* in_sizes, int n_in,
                              void* d_out, int out_size, void* d_ws, size_t ws_size,
                              hipStream_t stream) {
    const float* X        = (const float*)d_in[0];
    const int*   ei       = (const int*)d_in[1];
    const float* W        = (const float*)d_in[2];
    const float* att_src  = (const float*)d_in[3];
    const float* att_dst  = (const float*)d_in[4];
    const float* bias     = (const float*)d_in[5];
    const float* ln_gamma = (const float*)d_in[6];
    const float* ln_beta  = (const float*)d_in[7];
    float* out = (float*)d_out;

    const int N = in_sizes[0] / 128;
    const int E = in_sizes[1] / 2;
    const int NB = (N + DPB - 1) / DPB;

    char* ws = (char*)d_ws;
    size_t off = 0;
    auto alloc = [&](size_t bytes) {
        size_t o = off;
        off += (bytes + 255) & ~(size_t)255;
        return o;
    };
    unsigned int* xp     = (unsigned int*)(ws + alloc((size_t)N * 64 * 4));
    float2* aS           = (float2*)(ws + alloc((size_t)N * 8));
    float2* aD           = (float2*)(ws + alloc((size_t)N * 8));
    unsigned int* tmp    = (unsigned int*)(ws + alloc((size_t)NBIN2 * BCAP2 * 4));
    int* binCursor       = (int*)(ws + alloc((size_t)NBIN2 * CURPAD * 4));

    hipMemsetAsync(binCursor, 0, (size_t)NBIN2 * CURPAD * 4, stream);
    k_gemm<<<(N + 63) / 64, 256, 0, stream>>>(X, W, att_src, att_dst, xp, aS, aD, N);
    k_scatter<<<(E + SCHUNK - 1) / SCHUNK, 256, 0, stream>>>(ei, binCursor, tmp, E);
    k_fused<<<NB, 256, 0, stream>>>(xp, aS, aD, tmp, binCursor,
                                    bias, ln_gamma, ln_beta, out, N);
}

// Round 6
// 225.102 us; speedup vs baseline: 1.1149x; 1.1149x over previous
//
#include <hip/hip_runtime.h>
#include <hip/hip_bf16.h>

#define NEG_SLOPE 0.2f
#define LN_EPS 1e-5f
#define SM_EPS 1e-16f

typedef __attribute__((ext_vector_type(8))) short bf16x8;
typedef __attribute__((ext_vector_type(4))) float f32x4;

__device__ inline unsigned short f2bf(float f) {
    unsigned u = __float_as_uint(f);
    return (unsigned short)((u + 0x7FFFu + ((u >> 16) & 1u)) >> 16);
}
__device__ inline float bf_lo(unsigned int v) { return __uint_as_float(v << 16); }
__device__ inline float bf_hi(unsigned int v) { return __uint_as_float(v & 0xffff0000u); }
__device__ inline float rdlane(float v, int l) {
    return __uint_as_float(__builtin_amdgcn_readlane(__float_as_uint(v), l));
}

#define NBIN 512           // bins = dst>>8 (256 dsts per bin); ~391 occupied at N=100k
#define BCAP 4864          // slots per bin: mean E/391 ~= 4092, sigma ~64 -> +12 sigma
#define SCHUNK 4096        // edges per scatter block (16/thread); gather-free streaming
#define CURPAD 16          // binCursor stride in ints -> one counter per 64B line

// ---------------------------------------------------------------------------
// K1: bf16-MFMA GEMM + attention dots + bf16 pack. Block 0 initializes the
// line-padded binCursor (k_scatter runs strictly after this kernel).
// ---------------------------------------------------------------------------
__global__ __launch_bounds__(256) void k_gemm(const float* __restrict__ X,
                                              const float* __restrict__ W,
                                              const float* __restrict__ att_src,
                                              const float* __restrict__ att_dst,
                                              unsigned int* __restrict__ xp,
                                              float2* __restrict__ aS,
                                              float2* __restrict__ aD,
                                              int* __restrict__ binCursor, int N) {
    __shared__ unsigned short Ws[128 * 136];
    __shared__ unsigned short Xs[64 * 136];
    const int t = threadIdx.x;
    const int b0 = blockIdx.x * 64;
    const int lane = t & 63;
    const int w = t >> 6;
    const int c15 = lane & 15;
    const int quad = lane >> 4;

    if (blockIdx.x == 0) {
        for (int i = t; i < NBIN; i += 256) binCursor[i * CURPAD] = i * BCAP;
    }

#pragma unroll
    for (int i = 0; i < 16; ++i) {
        int f = i * 256 + t;
        int nr = f >> 5;
        int q = f & 31;
        float4 v = reinterpret_cast<const float4*>(W)[nr * 32 + q];
        ushort4 b;
        b.x = f2bf(v.x); b.y = f2bf(v.y); b.z = f2bf(v.z); b.w = f2bf(v.w);
        *reinterpret_cast<ushort4*>(&Ws[nr * 136 + q * 4]) = b;
    }
#pragma unroll
    for (int i = 0; i < 8; ++i) {
        int f = i * 256 + t;
        int m = f >> 5;
        int q = f & 31;
        int gr = b0 + m;
        if (gr >= N) gr = N - 1;
        float4 v = reinterpret_cast<const float4*>(X)[(size_t)gr * 32 + q];
        ushort4 b;
        b.x = f2bf(v.x); b.y = f2bf(v.y); b.z = f2bf(v.z); b.w = f2bf(v.w);
        *reinterpret_cast<ushort4*>(&Xs[m * 136 + q * 4]) = b;
    }
    __syncthreads();

    f32x4 acc[8];
#pragma unroll
    for (int ct = 0; ct < 8; ++ct) acc[ct] = (f32x4){0.f, 0.f, 0.f, 0.f};

#pragma unroll
    for (int kc = 0; kc < 4; ++kc) {
        bf16x8 af = *reinterpret_cast<const bf16x8*>(
            &Xs[(w * 16 + c15) * 136 + kc * 32 + quad * 8]);
#pragma unroll
        for (int ct = 0; ct < 8; ++ct) {
            bf16x8 bfr = *reinterpret_cast<const bf16x8*>(
                &Ws[(ct * 16 + c15) * 136 + kc * 32 + quad * 8]);
            acc[ct] = __builtin_amdgcn_mfma_f32_16x16x32_bf16(af, bfr, acc[ct], 0, 0, 0);
        }
    }

    float attS[8], attD[8];
#pragma unroll
    for (int ct = 0; ct < 8; ++ct) {
        attS[ct] = att_src[ct * 16 + c15];
        attD[ct] = att_dst[ct * 16 + c15];
    }

#pragma unroll
    for (int r = 0; r < 4; ++r) {
        int row = b0 + w * 16 + quad * 4 + r;
        float s0 = 0.f, s1 = 0.f, d0 = 0.f, d1 = 0.f;
#pragma unroll
        for (int ct = 0; ct < 4; ++ct) {
            s0 += acc[ct][r] * attS[ct];
            d0 += acc[ct][r] * attD[ct];
            s1 += acc[ct + 4][r] * attS[ct + 4];
            d1 += acc[ct + 4][r] * attD[ct + 4];
        }
#pragma unroll
        for (int o = 1; o < 16; o <<= 1) {
            s0 += __shfl_xor(s0, o);
            s1 += __shfl_xor(s1, o);
            d0 += __shfl_xor(d0, o);
            d1 += __shfl_xor(d1, o);
        }
        if (row < N) {
#pragma unroll
            for (int ct = 0; ct < 4; ++ct) {
                unsigned int p = (unsigned int)f2bf(acc[ct][r]) |
                                 ((unsigned int)f2bf(acc[ct + 4][r]) << 16);
                xp[(size_t)row * 64 + ct * 16 + c15] = p;
            }
            if (c15 == 0) {
                aS[row] = make_float2(s0, s1);
                aD[row] = make_float2(d0, d1);
            }
        }
    }
}

// ---------------------------------------------------------------------------
// k_scatter: pure streaming binner. 16 edges per thread; payload is 4B
// {(dst&255)<<24 | src}.
// Pass 1: LDS chunk-histogram; reserve per-(block,bin) ranges via one global
// atomicAdd per non-empty bin (line-padded cursors -> no line contention).
// Pass 2: scatter; runs of ~10 x 4B per (block,bin).
// ---------------------------------------------------------------------------
__global__ __launch_bounds__(256) void k_scatter(const int* __restrict__ ei,
                                                 int* __restrict__ binCursor,
                                                 unsigned int* __restrict__ tmp,
                                                 int E) {
    __shared__ int off[NBIN];
    const int t = threadIdx.x;
    const int base = blockIdx.x * SCHUNK;

    int bn[16];
    unsigned int pe[16];
#pragma unroll
    for (int k = 0; k < 16; ++k) {
        int i = base + k * 256 + t;
        if (i < E) {
            int s = ei[i];
            int d = ei[E + i];
            bn[k] = d >> 8;
            pe[k] = ((unsigned)(d & 255) << 24) | (unsigned)s;
        } else {
            bn[k] = -1;
        }
    }

    for (int i = t; i < NBIN; i += 256) off[i] = 0;
    __syncthreads();
#pragma unroll
    for (int k = 0; k < 16; ++k)
        if (bn[k] >= 0) atomicAdd(&off[bn[k]], 1);
    __syncthreads();
    for (int i = t; i < NBIN; i += 256) {
        int h = off[i];
        off[i] = h ? atomicAdd(&binCursor[i * CURPAD], h) : 0;
    }
    __syncthreads();
#pragma unroll
    for (int k = 0; k < 16; ++k) {
        if (bn[k] >= 0) {
            int p = atomicAdd(&off[bn[k]], 1);
            tmp[p] = pe[k];
        }
    }
}

// ---------------------------------------------------------------------------
// k_bucket: one block per 256-dst bin, 512 threads. P1: read tmp slice
// (coalesced, 4B/edge), LDS cnt histogram. Scan -> local offsets, packed
// rowPtr {beg | cnt<<22}. P2: re-read tmp (L2-hot), permute into csr
// (4B src-only entries, padded per-bin layout).
// ---------------------------------------------------------------------------
__global__ __launch_bounds__(512) void k_bucket(const unsigned int* __restrict__ tmp,
                                                const int* __restrict__ binCursor,
                                                unsigned int* __restrict__ csr,
                                                unsigned int* __restrict__ rowPtr,
                                                int N) {
    __shared__ int cnt[256];
    __shared__ int cur[256];
    __shared__ int lds[4];
    const int t = threadIdx.x;
    const int b = blockIdx.x;
    const int start = b * BCAP;
    int m = binCursor[b * CURPAD] - start;
    if (m > BCAP) m = BCAP;   // statistically unreachable guard

    if (t < 256) cnt[t] = 0;
    __syncthreads();

    for (int k = t; k < m; k += 512) {
        atomicAdd(&cnt[tmp[start + k] >> 24], 1);
    }
    __syncthreads();

    const int lane = t & 63, w = t >> 6;
    int v = 0, incl = 0;
    if (t < 256) {                 // waves 0-3 fully active -> shfl safe
        v = cnt[t];
        incl = v;
#pragma unroll
        for (int o = 1; o < 64; o <<= 1) {
            int u = __shfl_up(incl, o);
            if (lane >= o) incl += u;
        }
        if (lane == 63) lds[w] = incl;
    }
    __syncthreads();
    if (t == 0) {
        int run = 0;
        for (int i = 0; i < 4; ++i) { int tv = lds[i]; lds[i] = run; run += tv; }
    }
    __syncthreads();
    if (t < 256) {
        int excl = lds[w] + incl - v;
        cur[t] = excl;
        int d = b * 256 + t;
        if (d < N) rowPtr[d] = (unsigned)(start + excl) | ((unsigned)v << 22);
    }
    __syncthreads();

    for (int k = t; k < m; k += 512) {
        unsigned int e = tmp[start + k];
        int p = atomicAdd(&cur[e >> 24], 1);
        csr[start + p] = e & 0x00FFFFFFu;
    }
}

// ---------------------------------------------------------------------------
// K5: per-dst aggregation + bias + LayerNorm. 16-edge batches (round-5
// lesson: LDS fusion loses to this pipeline; round-4 k_agg was issue-bound
// at 84% VALU with only 8 gathers in flight). cc[] srcs are wave-uniform
// (SGPR s_loads) so 16 gathers cost only 16 dest VGPRs -> MLP doubles; the
// per-batch exp machinery (myc load, aS gather, one v_exp_f32) amortizes
// over 16 edges: lane l = edge (l&15), head ((l>>4)&1). Clamp-to-last is
// SALU on uniform addresses and keeps overshoot gathers L1-hot. Weights
// broadcast via readlane; denominators lane-local, folded once at the end.
// ---------------------------------------------------------------------------
__global__ __launch_bounds__(256) void k_agg(const unsigned int* __restrict__ xp,
                                             const float2* __restrict__ aS,
                                             const float2* __restrict__ aD,
                                             const unsigned int* __restrict__ rowPtr,
                                             const unsigned int* __restrict__ csr,
                                             const float* __restrict__ bias,
                                             const float* __restrict__ gamma,
                                             const float* __restrict__ beta,
                                             float* __restrict__ out, int N) {
    const int w = threadIdx.x >> 6, lane = threadIdx.x & 63;
    const int n = blockIdx.x * 4 + w;
    if (n >= N) return;

    const float* aSf = (const float*)aS;

    float2 a = aS[n];
    float2 ad2 = aD[n];
    float f0 = a.x + ad2.x; f0 = fmaxf(f0, NEG_SLOPE * f0);
    float f1 = a.y + ad2.y; f1 = fmaxf(f1, NEG_SLOPE * f1);
    float us0 = __expf(f0), us1 = __expf(f1);

    unsigned int vself = xp[((unsigned)n << 6) | lane];
    float S0 = us0 * bf_lo(vself);
    float S1 = us1 * bf_hi(vself);
    float D0 = us0, D1 = us1;

    unsigned int pr = rowPtr[n];
    const int jb = (int)(pr & 0x3FFFFFu);
    const int deg = (int)(pr >> 22);
    const int je = jb + deg;
    const int nb = (deg + 15) >> 4;

    const int eq = lane & 15;                // edge slot this lane exp's
    const int hsel = (lane >> 4) & 1;        // head this lane exp's
    const float adv = hsel ? ad2.y : ad2.x;

    float Dacc = 0.f;
    int j = jb;
    unsigned int cc[16];                     // uniform: srcs for xp addressing
    unsigned int myc = 0;                    // per-lane: src of edge eq

    if (nb > 0) {
        int ju = __builtin_amdgcn_readfirstlane(jb);
        int last = __builtin_amdgcn_readfirstlane(je - 1);
#pragma unroll
        for (int q = 0; q < 16; ++q) {
            int idx = ju + q; if (idx > last) idx = last;
            cc[q] = csr[idx];
        }
        int mi = ju + eq; if (mi > last) mi = last;
        myc = csr[mi];
    }

    for (int bI = 0; bI < nb; ++bI) {
        const int limit = je - j;            // uniform; >=16 except last batch
        // per-lane 4B gather: aS[src].head for this lane's (edge, head)
        float av = aSf[(myc << 1) | (unsigned)hsel];
        unsigned int v[16];
#pragma unroll
        for (int q = 0; q < 16; ++q)
            v[q] = (xp + ((size_t)cc[q] << 6))[lane];
        // prefetch next batch's csr entries (dummy re-read of jb on last iter)
        unsigned int cn[16], mn;
        {
            int jn = (bI + 1 < nb) ? (j + 16) : jb;
            int ju = __builtin_amdgcn_readfirstlane(jn);
            int last = __builtin_amdgcn_readfirstlane(je - 1);
#pragma unroll
            for (int q = 0; q < 16; ++q) {
                int idx = ju + q; if (idx > last) idx = last;
                cn[q] = csr[idx];
            }
            int mi = ju + eq; if (mi > last) mi = last;
            mn = csr[mi];
        }
        float g = av + adv; g = fmaxf(g, NEG_SLOPE * g);
        float u = (eq < limit) ? __expf(g) : 0.f;   // mask tail edges
        Dacc += u;
#pragma unroll
        for (int q = 0; q < 16; ++q) {
            float u0 = rdlane(u, q);
            float u1 = rdlane(u, q + 16);
            S0 = fmaf(u0, bf_lo(v[q]), S0);
            S1 = fmaf(u1, bf_hi(v[q]), S1);
        }
#pragma unroll
        for (int q = 0; q < 16; ++q) cc[q] = cn[q];
        myc = mn;
        j += 16;
    }

    // fold lane-local denominator partials: lanes 0-15 hold head0, 16-31 head1
    Dacc += __shfl_xor(Dacc, 1);
    Dacc += __shfl_xor(Dacc, 2);
    Dacc += __shfl_xor(Dacc, 4);
    Dacc += __shfl_xor(Dacc, 8);
    D0 += rdlane(Dacc, 0);
    D1 += rdlane(Dacc, 16);

    float o = (0.5f / (D0 + SM_EPS)) * S0 + (0.5f / (D1 + SM_EPS)) * S1 + bias[lane];

    float mu = o;
#pragma unroll
    for (int d = 32; d > 0; d >>= 1) mu += __shfl_xor(mu, d);
    mu *= (1.0f / 64.0f);
    float dv = o - mu;
    float var = dv * dv;
#pragma unroll
    for (int d = 32; d > 0; d >>= 1) var += __shfl_xor(var, d);
    var *= (1.0f / 64.0f);
    out[(size_t)n * 64 + lane] = dv * rsqrtf(var + LN_EPS) * gamma[lane] + beta[lane];
}

// ---------------------------------------------------------------------------
extern "C" void kernel_launch(void* const* d_in, const int* in_sizes, int n_in,
                              void* d_out, int out_size, void* d_ws, size_t ws_size,
                              hipStream_t stream) {
    const float* X        = (const float*)d_in[0];
    const int*   ei       = (const int*)d_in[1];
    const float* W        = (const float*)d_in[2];
    const float* att_src  = (const float*)d_in[3];
    const float* att_dst  = (const float*)d_in[4];
    const float* bias     = (const float*)d_in[5];
    const float* ln_gamma = (const float*)d_in[6];
    const float* ln_beta  = (const float*)d_in[7];
    float* out = (float*)d_out;

    const int N = in_sizes[0] / 128;
    const int E = in_sizes[1] / 2;
    const int NBUCK = (N + 255) / 256;

    char* ws = (char*)d_ws;
    size_t off = 0;
    auto alloc = [&](size_t bytes) {
        size_t o = off;
        off += (bytes + 255) & ~(size_t)255;
        return o;
    };
    unsigned int* xp     = (unsigned int*)(ws + alloc((size_t)N * 64 * 4));
    float2* aS           = (float2*)(ws + alloc((size_t)N * 8));
    float2* aD           = (float2*)(ws + alloc((size_t)N * 8));
    unsigned int* rowPtr = (unsigned int*)(ws + alloc((size_t)N * 4));
    unsigned int* csr    = (unsigned int*)(ws + alloc((size_t)NBIN * BCAP * 4));
    unsigned int* tmp    = (unsigned int*)(ws + alloc((size_t)NBIN * BCAP * 4));
    int* binCursor       = (int*)(ws + alloc(NBIN * CURPAD * 4));

    k_gemm<<<(N + 63) / 64, 256, 0, stream>>>(X, W, att_src, att_dst, xp, aS, aD,
                                              binCursor, N);
    k_scatter<<<(E + SCHUNK - 1) / SCHUNK, 256, 0, stream>>>(ei, binCursor, tmp, E);
    k_bucket<<<NBUCK, 512, 0, stream>>>(tmp, binCursor, csr, rowPtr, N);
    k_agg<<<(N + 3) / 4, 256, 0, stream>>>(xp, aS, aD, rowPtr, csr,
                                           bias, ln_gamma, ln_beta, out, N);
}

// Round 7
// 214.990 us; speedup vs baseline: 1.1673x; 1.0470x over previous
//
#include <hip/hip_runtime.h>
#include <hip/hip_bf16.h>

#define NEG_SLOPE 0.2f
#define LN_EPS 1e-5f
#define SM_EPS 1e-16f

typedef __attribute__((ext_vector_type(8))) short bf16x8;
typedef __attribute__((ext_vector_type(4))) float f32x4;

__device__ inline unsigned short f2bf(float f) {
    unsigned u = __float_as_uint(f);
    return (unsigned short)((u + 0x7FFFu + ((u >> 16) & 1u)) >> 16);
}
__device__ inline float bf_lo(unsigned int v) { return __uint_as_float(v << 16); }
__device__ inline float bf_hi(unsigned int v) { return __uint_as_float(v & 0xffff0000u); }
__device__ inline float rdlane(float v, int l) {
    return __uint_as_float(__builtin_amdgcn_readlane(__float_as_uint(v), l));
}

#define NBIN 512           // bins = dst>>8 (256 dsts per bin); ~391 occupied at N=100k
#define BCAP 4864          // slots per bin: mean E/391 ~= 4092, sigma ~64 -> +12 sigma
#define SCHUNK 4096        // edges per scatter block (16/thread)
#define CURPAD 16          // binCursor stride in ints -> one counter per 64B line

// ---------------------------------------------------------------------------
// k_gs: heterogeneous fused dispatch. Blocks [0,SB) run the scatter body
// (reads ei only), blocks [SB,SB+GB) run the GEMM body (reads X,W only) —
// the two are data-independent, so they overlap on the machine instead of
// serializing: gemm is MFMA/VALU-heavy, scatter is latency/LDS-atomic-heavy.
// LDS aliased via one 52KB pool (union, not sum -> gemm keeps 3 blocks/CU).
// binCursor is bin-RELATIVE, initialized by hipMemsetAsync before launch.
// ---------------------------------------------------------------------------
__global__ __launch_bounds__(256) void k_gs(const float* __restrict__ X,
                                            const float* __restrict__ W,
                                            const float* __restrict__ att_src,
                                            const float* __restrict__ att_dst,
                                            unsigned int* __restrict__ xp,
                                            float2* __restrict__ aS,
                                            float2* __restrict__ aD,
                                            const int* __restrict__ ei,
                                            int* __restrict__ binCursor,
                                            unsigned int* __restrict__ tmp,
                                            int N, int E, int SB) {
    __shared__ __align__(16) char smem[52224];
    const int t = threadIdx.x;

    if ((int)blockIdx.x < SB) {
        // ---------------- scatter body: pure streaming binner ----------------
        int* off = (int*)smem;
        const int base = blockIdx.x * SCHUNK;

        int bn[16];
        unsigned int pe[16];
#pragma unroll
        for (int k = 0; k < 16; ++k) {
            int i = base + k * 256 + t;
            if (i < E) {
                int s = ei[i];
                int d = ei[E + i];
                bn[k] = d >> 8;
                pe[k] = ((unsigned)(d & 255) << 24) | (unsigned)s;
            } else {
                bn[k] = -1;
            }
        }

        for (int i = t; i < NBIN; i += 256) off[i] = 0;
        __syncthreads();
#pragma unroll
        for (int k = 0; k < 16; ++k)
            if (bn[k] >= 0) atomicAdd(&off[bn[k]], 1);
        __syncthreads();
        for (int i = t; i < NBIN; i += 256) {
            int h = off[i];
            off[i] = h ? (atomicAdd(&binCursor[i * CURPAD], h) + i * BCAP) : 0;
        }
        __syncthreads();
#pragma unroll
        for (int k = 0; k < 16; ++k) {
            if (bn[k] >= 0) {
                int p = atomicAdd(&off[bn[k]], 1);
                tmp[p] = pe[k];
            }
        }
        return;
    }

    // ---------------- GEMM body: bf16 MFMA + attention dots ----------------
    unsigned short* Ws = (unsigned short*)smem;                 // 128*136 ushort
    unsigned short* Xs = (unsigned short*)(smem + 34816);       //  64*136 ushort
    const int b0 = ((int)blockIdx.x - SB) * 64;
    const int lane = t & 63;
    const int w = t >> 6;
    const int c15 = lane & 15;
    const int quad = lane >> 4;

#pragma unroll
    for (int i = 0; i < 16; ++i) {
        int f = i * 256 + t;
        int nr = f >> 5;
        int q = f & 31;
        float4 v = reinterpret_cast<const float4*>(W)[nr * 32 + q];
        ushort4 b;
        b.x = f2bf(v.x); b.y = f2bf(v.y); b.z = f2bf(v.z); b.w = f2bf(v.w);
        *reinterpret_cast<ushort4*>(&Ws[nr * 136 + q * 4]) = b;
    }
#pragma unroll
    for (int i = 0; i < 8; ++i) {
        int f = i * 256 + t;
        int m = f >> 5;
        int q = f & 31;
        int gr = b0 + m;
        if (gr >= N) gr = N - 1;
        float4 v = reinterpret_cast<const float4*>(X)[(size_t)gr * 32 + q];
        ushort4 b;
        b.x = f2bf(v.x); b.y = f2bf(v.y); b.z = f2bf(v.z); b.w = f2bf(v.w);
        *reinterpret_cast<ushort4*>(&Xs[m * 136 + q * 4]) = b;
    }
    __syncthreads();

    f32x4 acc[8];
#pragma unroll
    for (int ct = 0; ct < 8; ++ct) acc[ct] = (f32x4){0.f, 0.f, 0.f, 0.f};

#pragma unroll
    for (int kc = 0; kc < 4; ++kc) {
        bf16x8 af = *reinterpret_cast<const bf16x8*>(
            &Xs[(w * 16 + c15) * 136 + kc * 32 + quad * 8]);
#pragma unroll
        for (int ct = 0; ct < 8; ++ct) {
            bf16x8 bfr = *reinterpret_cast<const bf16x8*>(
                &Ws[(ct * 16 + c15) * 136 + kc * 32 + quad * 8]);
            acc[ct] = __builtin_amdgcn_mfma_f32_16x16x32_bf16(af, bfr, acc[ct], 0, 0, 0);
        }
    }

    float attS[8], attD[8];
#pragma unroll
    for (int ct = 0; ct < 8; ++ct) {
        attS[ct] = att_src[ct * 16 + c15];
        attD[ct] = att_dst[ct * 16 + c15];
    }

#pragma unroll
    for (int r = 0; r < 4; ++r) {
        int row = b0 + w * 16 + quad * 4 + r;
        float s0 = 0.f, s1 = 0.f, d0 = 0.f, d1 = 0.f;
#pragma unroll
        for (int ct = 0; ct < 4; ++ct) {
            s0 += acc[ct][r] * attS[ct];
            d0 += acc[ct][r] * attD[ct];
            s1 += acc[ct + 4][r] * attS[ct + 4];
            d1 += acc[ct + 4][r] * attD[ct + 4];
        }
#pragma unroll
        for (int o = 1; o < 16; o <<= 1) {
            s0 += __shfl_xor(s0, o);
            s1 += __shfl_xor(s1, o);
            d0 += __shfl_xor(d0, o);
            d1 += __shfl_xor(d1, o);
        }
        if (row < N) {
#pragma unroll
            for (int ct = 0; ct < 4; ++ct) {
                unsigned int p = (unsigned int)f2bf(acc[ct][r]) |
                                 ((unsigned int)f2bf(acc[ct + 4][r]) << 16);
                xp[(size_t)row * 64 + ct * 16 + c15] = p;
            }
            if (c15 == 0) {
                aS[row] = make_float2(s0, s1);
                aD[row] = make_float2(d0, d1);
            }
        }
    }
}

// ---------------------------------------------------------------------------
// k_bucket: one block per 256-dst bin, 512 threads. P1: read tmp slice
// (coalesced, 4B/edge), LDS cnt histogram. Scan -> local offsets, packed
// rowPtr {beg | cnt<<22}. P2: re-read tmp (L2-hot), permute into csr
// (4B src-only entries, padded per-bin layout). binCursor is bin-relative.
// ---------------------------------------------------------------------------
__global__ __launch_bounds__(512) void k_bucket(const unsigned int* __restrict__ tmp,
                                                const int* __restrict__ binCursor,
                                                unsigned int* __restrict__ csr,
                                                unsigned int* __restrict__ rowPtr,
                                                int N) {
    __shared__ int cnt[256];
    __shared__ int cur[256];
    __shared__ int lds[4];
    const int t = threadIdx.x;
    const int b = blockIdx.x;
    const int start = b * BCAP;
    int m = binCursor[b * CURPAD];
    if (m > BCAP) m = BCAP;   // statistically unreachable guard

    if (t < 256) cnt[t] = 0;
    __syncthreads();

    for (int k = t; k < m; k += 512) {
        atomicAdd(&cnt[tmp[start + k] >> 24], 1);
    }
    __syncthreads();

    const int lane = t & 63, w = t >> 6;
    int v = 0, incl = 0;
    if (t < 256) {                 // waves 0-3 fully active -> shfl safe
        v = cnt[t];
        incl = v;
#pragma unroll
        for (int o = 1; o < 64; o <<= 1) {
            int u = __shfl_up(incl, o);
            if (lane >= o) incl += u;
        }
        if (lane == 63) lds[w] = incl;
    }
    __syncthreads();
    if (t == 0) {
        int run = 0;
        for (int i = 0; i < 4; ++i) { int tv = lds[i]; lds[i] = run; run += tv; }
    }
    __syncthreads();
    if (t < 256) {
        int excl = lds[w] + incl - v;
        cur[t] = excl;
        int d = b * 256 + t;
        if (d < N) rowPtr[d] = (unsigned)(start + excl) | ((unsigned)v << 22);
    }
    __syncthreads();

    for (int k = t; k < m; k += 512) {
        unsigned int e = tmp[start + k];
        int p = atomicAdd(&cur[e >> 24], 1);
        csr[start + p] = e & 0x00FFFFFFu;
    }
}

// ---------------------------------------------------------------------------
// K5: per-dst aggregation + bias + LayerNorm. Round-4 8-edge lane-parallel
// version, verbatim (round-6 lesson: 16-edge batches waste tail slots at
// mean deg ~17 -> 74.4us beats 82us). Lane l exp's edge (l&7), head
// ((l>>3)&1) -> one v_exp_f32 per batch; weights broadcast via readlane;
// denominators lane-local, folded after the loop; csr prefetch pipelined.
// ---------------------------------------------------------------------------
__global__ __launch_bounds__(256) void k_agg(const unsigned int* __restrict__ xp,
                                             const float2* __restrict__ aS,
                                             const float2* __restrict__ aD,
                                             const unsigned int* __restrict__ rowPtr,
                                             const unsigned int* __restrict__ csr,
                                             const float* __restrict__ bias,
                                             const float* __restrict__ gamma,
                                             const float* __restrict__ beta,
                                             float* __restrict__ out, int N) {
    const int w = threadIdx.x >> 6, lane = threadIdx.x & 63;
    const int n = blockIdx.x * 4 + w;
    if (n >= N) return;

    const float* aSf = (const float*)aS;

    float2 a = aS[n];
    float2 ad2 = aD[n];
    float f0 = a.x + ad2.x; f0 = fmaxf(f0, NEG_SLOPE * f0);
    float f1 = a.y + ad2.y; f1 = fmaxf(f1, NEG_SLOPE * f1);
    float us0 = __expf(f0), us1 = __expf(f1);

    unsigned int vself = xp[((unsigned)n << 6) | lane];
    float S0 = us0 * bf_lo(vself);
    float S1 = us1 * bf_hi(vself);
    float D0 = us0, D1 = us1;

    unsigned int pr = rowPtr[n];
    const int jb = (int)(pr & 0x3FFFFFu);
    const int deg = (int)(pr >> 22);
    const int je = jb + deg;
    const int nb = (deg + 7) >> 3;

    const int eq = lane & 7;                 // edge slot this lane exp's
    const int hsel = (lane >> 3) & 1;        // head this lane exp's
    const float adv = hsel ? ad2.y : ad2.x;

    float Dacc = 0.f;
    int j = jb;
    unsigned int cc[8];                      // uniform: srcs for xp addressing
    unsigned int myc = 0;                    // per-lane: src of edge eq

    if (nb > 0) {
        int ju = __builtin_amdgcn_readfirstlane(jb);
        int last = __builtin_amdgcn_readfirstlane(je - 1);
#pragma unroll
        for (int q = 0; q < 8; ++q) {
            int idx = ju + q; if (idx > last) idx = last;
            cc[q] = csr[idx];
        }
        int mi = ju + eq; if (mi > last) mi = last;
        myc = csr[mi];
    }

    for (int bI = 0; bI < nb; ++bI) {
        const int limit = je - j;            // uniform; >=8 except last batch
        // per-lane 4B gather: aS[src].head for this lane's (edge, head)
        float av = aSf[(myc << 1) | (unsigned)hsel];
        unsigned int v[8];
#pragma unroll
        for (int q = 0; q < 8; ++q)
            v[q] = (xp + ((size_t)cc[q] << 6))[lane];
        // prefetch next batch's csr entries (dummy re-read of jb on last iter)
        unsigned int cn[8], mn;
        {
            int jn = (bI + 1 < nb) ? (j + 8) : jb;
            int ju = __builtin_amdgcn_readfirstlane(jn);
            int last = __builtin_amdgcn_readfirstlane(je - 1);
#pragma unroll
            for (int q = 0; q < 8; ++q) {
                int idx = ju + q; if (idx > last) idx = last;
                cn[q] = csr[idx];
            }
            int mi = ju + eq; if (mi > last) mi = last;
            mn = csr[mi];
        }
        float g = av + adv; g = fmaxf(g, NEG_SLOPE * g);
        float u = (eq < limit) ? __expf(g) : 0.f;   // mask tail edges
        Dacc += u;
#pragma unroll
        for (int q = 0; q < 8; ++q) {
            float u0 = rdlane(u, q);
            float u1 = rdlane(u, q + 8);
            S0 = fmaf(u0, bf_lo(v[q]), S0);
            S1 = fmaf(u1, bf_hi(v[q]), S1);
        }
#pragma unroll
        for (int q = 0; q < 8; ++q) cc[q] = cn[q];
        myc = mn;
        j += 8;
    }

    // fold lane-local denominator partials: lanes 0-7 hold head0, 8-15 head1
    Dacc += __shfl_xor(Dacc, 1);
    Dacc += __shfl_xor(Dacc, 2);
    Dacc += __shfl_xor(Dacc, 4);
    D0 += rdlane(Dacc, 0);
    D1 += rdlane(Dacc, 8);

    float o = (0.5f / (D0 + SM_EPS)) * S0 + (0.5f / (D1 + SM_EPS)) * S1 + bias[lane];

    float mu = o;
#pragma unroll
    for (int d = 32; d > 0; d >>= 1) mu += __shfl_xor(mu, d);
    mu *= (1.0f / 64.0f);
    float dv = o - mu;
    float var = dv * dv;
#pragma unroll
    for (int d = 32; d > 0; d >>= 1) var += __shfl_xor(var, d);
    var *= (1.0f / 64.0f);
    out[(size_t)n * 64 + lane] = dv * rsqrtf(var + LN_EPS) * gamma[lane] + beta[lane];
}

// ---------------------------------------------------------------------------
extern "C" void kernel_launch(void* const* d_in, const int* in_sizes, int n_in,
                              void* d_out, int out_size, void* d_ws, size_t ws_size,
                              hipStream_t stream) {
    const float* X        = (const float*)d_in[0];
    const int*   ei       = (const int*)d_in[1];
    const float* W        = (const float*)d_in[2];
    const float* att_src  = (const float*)d_in[3];
    const float* att_dst  = (const float*)d_in[4];
    const float* bias     = (const float*)d_in[5];
    const float* ln_gamma = (const float*)d_in[6];
    const float* ln_beta  = (const float*)d_in[7];
    float* out = (float*)d_out;

    const int N = in_sizes[0] / 128;
    const int E = in_sizes[1] / 2;
    const int NBUCK = (N + 255) / 256;
    const int SB = (E + SCHUNK - 1) / SCHUNK;
    const int GB = (N + 63) / 64;

    char* ws = (char*)d_ws;
    size_t off = 0;
    auto alloc = [&](size_t bytes) {
        size_t o = off;
        off += (bytes + 255) & ~(size_t)255;
        return o;
    };
    unsigned int* xp     = (unsigned int*)(ws + alloc((size_t)N * 64 * 4));
    float2* aS           = (float2*)(ws + alloc((size_t)N * 8));
    float2* aD           = (float2*)(ws + alloc((size_t)N * 8));
    unsigned int* rowPtr = (unsigned int*)(ws + alloc((size_t)N * 4));
    unsigned int* csr    = (unsigned int*)(ws + alloc((size_t)NBIN * BCAP * 4));
    unsigned int* tmp    = (unsigned int*)(ws + alloc((size_t)NBIN * BCAP * 4));
    int* binCursor       = (int*)(ws + alloc(NBIN * CURPAD * 4));

    hipMemsetAsync(binCursor, 0, (size_t)NBIN * CURPAD * 4, stream);
    k_gs<<<SB + GB, 256, 0, stream>>>(X, W, att_src, att_dst, xp, aS, aD,
                                      ei, binCursor, tmp, N, E, SB);
    k_bucket<<<NBUCK, 512, 0, stream>>>(tmp, binCursor, csr, rowPtr, N);
    k_agg<<<(N + 3) / 4, 256, 0, stream>>>(xp, aS, aD, rowPtr, csr,
                                           bias, ln_gamma, ln_beta, out, N);
}